// Round 9
// baseline (439.911 us; speedup 1.0000x reference)
//
#include <hip/hip_runtime.h>
#include <stdint.h>

// Problem constants (match reference)
#define NE   64      // experts
#define HD   2048    // hidden dim
#define ND   512     // difficulty head inner dim
#define NTOK 16384   // B*S = 4*4096

typedef __attribute__((ext_vector_type(4))) float   fv4;
typedef __attribute__((ext_vector_type(8))) short   bf16x8;
typedef __attribute__((ext_vector_type(4))) float   f32x4;

// LDS 16B-unit index: row*4 + (q ^ ((row>>2)&3)).
__device__ inline int swz(int row, int q) {
  return row * 4 + (q ^ ((row >> 2) & 3));
}

// ---------- helpers ----------
__device__ inline unsigned short bf_rne(float x) {
  unsigned int u = __float_as_uint(x);
  return (unsigned short)((u + 0x7FFFu + ((u >> 16) & 1u)) >> 16);
}
__device__ inline float bf_to_f(unsigned short h) {
  return __uint_as_float((unsigned int)h << 16);
}
// exact 3-way truncation split: x == h + m + l (8+8+8 mantissa bits)
__device__ inline void split3(float x, unsigned short& h, unsigned short& m,
                              unsigned short& l) {
  unsigned int u = __float_as_uint(x);
  h = (unsigned short)(u >> 16);
  float r1 = x - __uint_as_float(u & 0xFFFF0000u);
  unsigned int um = __float_as_uint(r1);
  m = (unsigned short)(um >> 16);
  float r2 = r1 - __uint_as_float(um & 0xFFFF0000u);
  l = bf_rne(r2);
}

// async global->LDS 16B copy. Dest = wave-uniform base + lane*16. Source addr
// is per-lane (swizzle folded into the global address).
__device__ inline void gload16(const void* g, void* l) {
  __builtin_amdgcn_global_load_lds(
      (__attribute__((address_space(1))) void*)g,
      (__attribute__((address_space(3))) void*)l, 16, 0, 0);
}

// ---------- K0: w1 split + gw split3 + tiny zero (x2 + done-counter) ------
// lg is no longer zeroed: gate writes it with plain stores now.
__global__ __launch_bounds__(256)
void k_pre(const float* __restrict__ w1, unsigned short* __restrict__ w1h,
           unsigned short* __restrict__ w1l, const float* __restrict__ gw,
           unsigned short* __restrict__ gh, unsigned short* __restrict__ gm,
           unsigned short* __restrict__ gl, uint4* __restrict__ ztail) {
  const int b = blockIdx.x, t = threadIdx.x;
  if (b < 512) {
    // w1 fp32 -> bf16 hi/lo planes (rne)
    int i = (b * 256 + t) * 8;
    fv4 v0 = *(const fv4*)(w1 + i);
    fv4 v1 = *(const fv4*)(w1 + i + 4);
    union { unsigned short s[8]; uint4 v; } ph, pl;
#pragma unroll
    for (int j = 0; j < 8; ++j) {
      float x = (j < 4) ? v0[j] : v1[j - 4];
      unsigned short h = bf_rne(x);
      ph.s[j] = h;
      pl.s[j] = bf_rne(x - bf_to_f(h));
    }
    *(uint4*)(w1h + i) = ph.v;
    *(uint4*)(w1l + i) = pl.v;
  } else if (b < 576) {
    // gw fp32 -> 3 exact bf16 planes (h/m/l truncation split)
    int i = ((b - 512) * 256 + t) * 8;
    fv4 v0 = *(const fv4*)(gw + i);
    fv4 v1 = *(const fv4*)(gw + i + 4);
    union { unsigned short s[8]; uint4 v; } xh, xm, xl;
#pragma unroll
    for (int j = 0; j < 8; ++j) {
      float x = (j < 4) ? v0[j] : v1[j - 4];
      split3(x, xh.s[j], xm.s[j], xl.s[j]);
    }
    *(uint4*)(gh + i) = xh.v;
    *(uint4*)(gm + i) = xm.v;
    *(uint4*)(gl + i) = xl.v;
  } else {
    // zero x2 (65,536 B) + done-counter (16 B): 4097 uint4
    uint4 zz = {0u, 0u, 0u, 0u};
    for (int i = t; i < 4097; i += 256) ztail[i] = zz;
  }
}

// ---------- K1: fused gate + difficulty GEMMs, 768-block grid -------------
// R6 diagnosis refined: the 2-blocks/CU cap was GRID arithmetic (512 diff
// blocks = exactly 2/CU, z-major serializes kinds), not regs (3x164=492<=512)
// or LDS (3x40=120<=160). Fix at constant per-block work:
//  (a) gate merged per-tile: one block runs k-half0 chain (acc0) then k-half1
//      (acc1), plain-stores lg = acc0+acc1. fp32 add commutes -> bit-identical
//      to the old atomic p0+p1 accumulation, now deterministic. No atomics,
//      no lg zeroing. Gate blocks 512 -> 256.
//  (b) 768 blocks interleaved (gate at bid%3==0): 768 x 40KB = exactly 3
//      blocks/CU in the mixed window, gate(VALU)+diff(MFMA) co-resident.
// Diff body is R6-verbatim (x2 atomics kept: 8 contributors/token).
__global__ __launch_bounds__(256)
void k_main(const float* __restrict__ hs, const unsigned short* __restrict__ gh,
            const unsigned short* __restrict__ gm,
            const unsigned short* __restrict__ gl, float* __restrict__ lg,
            const unsigned short* __restrict__ w1h,
            const unsigned short* __restrict__ w1l, const float* __restrict__ b1,
            const float* __restrict__ w2, float* __restrict__ x2) {
  __shared__ __align__(16) unsigned short smem[20480];  // 40 KB union

  const int t = threadIdx.x;
  const int w = t >> 6, l = t & 63, l15 = l & 15, q = l >> 4;
  const int srow = t >> 2, sq = (t & 3) ^ ((t >> 4) & 3);
  const int bid = blockIdx.x;

  if (bid % 3 == 0) {
    // ================= gate body (both k-halves, atomic-free) ============
    unsigned short* sAh = smem;          // 256 units x 8 shorts
    unsigned short* sAm = smem + 2048;
    unsigned short* sAl = smem + 4096;
    unsigned short* sBh = smem + 6144;
    unsigned short* sBm = smem + 8192;
    unsigned short* sBl = smem + 10240;

    const int tokBase = (bid / 3) * 64;
    const int waveM = w & 1, waveN = w >> 1;

    f32x4 acc[2][2][2] = {};   // [half][rt][ct] — all static indices

#pragma unroll
    for (int h = 0; h < 2; ++h) {
      const int k0base = h * (HD / 2);
      for (int kb = 0; kb < 32; ++kb) {
        const int k0 = k0base + kb * 32;
        // A: fp32 load (issued first), split3 inline, ds_write
        const float* ga = hs + (size_t)(tokBase + srow) * HD + k0 + sq * 8;
        fv4 a0 = *(const fv4*)ga, a1 = *(const fv4*)(ga + 4);
        // B: 3 pre-split planes, async 16B DMA into linear LDS
        {
          const size_t gb = (size_t)srow * HD + k0 + sq * 8;
          gload16(gh + gb, &sBh[t * 8]);
          gload16(gm + gb, &sBm[t * 8]);
          gload16(gl + gb, &sBl[t * 8]);
        }
        {
          union { unsigned short s[8]; uint4 v; } xh, xm, xl;
#pragma unroll
          for (int j = 0; j < 8; ++j) {
            float x = (j < 4) ? a0[j] : a1[j - 4];
            split3(x, xh.s[j], xm.s[j], xl.s[j]);
          }
          *(uint4*)&sAh[t * 8] = xh.v;
          *(uint4*)&sAm[t * 8] = xm.v;
          *(uint4*)&sAl[t * 8] = xl.v;
        }
        __syncthreads();

        bf16x8 ah[2], am[2], al[2], bh[2], bm[2], bl[2];
#pragma unroll
        for (int rt = 0; rt < 2; ++rt) {
          int off = swz(waveM * 32 + rt * 16 + l15, q) * 8;
          ah[rt] = *(const bf16x8*)&sAh[off];
          am[rt] = *(const bf16x8*)&sAm[off];
          al[rt] = *(const bf16x8*)&sAl[off];
        }
#pragma unroll
        for (int ct = 0; ct < 2; ++ct) {
          int off = swz(waveN * 32 + ct * 16 + l15, q) * 8;
          bh[ct] = *(const bf16x8*)&sBh[off];
          bm[ct] = *(const bf16x8*)&sBm[off];
          bl[ct] = *(const bf16x8*)&sBl[off];
        }
#pragma unroll
        for (int rt = 0; rt < 2; ++rt)
#pragma unroll
          for (int ct = 0; ct < 2; ++ct) {
            acc[h][rt][ct] = __builtin_amdgcn_mfma_f32_16x16x32_bf16(al[rt], bh[ct], acc[h][rt][ct], 0, 0, 0);
            acc[h][rt][ct] = __builtin_amdgcn_mfma_f32_16x16x32_bf16(ah[rt], bl[ct], acc[h][rt][ct], 0, 0, 0);
            acc[h][rt][ct] = __builtin_amdgcn_mfma_f32_16x16x32_bf16(am[rt], bm[ct], acc[h][rt][ct], 0, 0, 0);
            acc[h][rt][ct] = __builtin_amdgcn_mfma_f32_16x16x32_bf16(am[rt], bh[ct], acc[h][rt][ct], 0, 0, 0);
            acc[h][rt][ct] = __builtin_amdgcn_mfma_f32_16x16x32_bf16(ah[rt], bm[ct], acc[h][rt][ct], 0, 0, 0);
            acc[h][rt][ct] = __builtin_amdgcn_mfma_f32_16x16x32_bf16(ah[rt], bh[ct], acc[h][rt][ct], 0, 0, 0);
          }
        __syncthreads();
      }
    }

    // plain store: p0 + p1 (bit-identical to the old 0+p0+p1 atomic result)
#pragma unroll
    for (int rt = 0; rt < 2; ++rt)
#pragma unroll
      for (int ct = 0; ct < 2; ++ct)
#pragma unroll
        for (int i = 0; i < 4; ++i)
          lg[(size_t)(tokBase + waveM * 32 + rt * 16 + q * 4 + i) * NE +
             waveN * 32 + ct * 16 + l15] = acc[0][rt][ct][i] + acc[1][rt][ct][i];
  } else {
    // ================= diff body (R6-verbatim) ===========================
    unsigned short* sAh = smem;           // 256 units
    unsigned short* sAl = smem + 2048;
    unsigned short* sBh = smem + 4096;    // 1024 units
    unsigned short* sBl = smem + 12288;

    const int db = bid - bid / 3 - 1;     // 0..511, bijective
    const int nBase = (db & 1) * 256;
    const int tokBase = (db >> 1) * 64;

    f32x4 acc[4][4] = {};

    for (int kb = 0; kb < HD / 32; ++kb) {
      const int k0 = kb * 32;
      // A: fp32 load (issued first), rne hi/lo split, ds_write
      const float* g = hs + (size_t)(tokBase + srow) * HD + k0 + sq * 8;
      fv4 v0 = *(const fv4*)g, v1 = *(const fv4*)(g + 4);
      // B: 1024 units per plane, 4 per thread, async 16B DMA
#pragma unroll
      for (int j = 0; j < 4; ++j) {
        int s = t + j * 256;
        int brow = s >> 2, bq = (s & 3) ^ ((s >> 4) & 3);
        const size_t gb = (size_t)(nBase + brow) * HD + k0 + bq * 8;
        gload16(w1h + gb, &sBh[s * 8]);
        gload16(w1l + gb, &sBl[s * 8]);
      }
      {
        union { unsigned short s[8]; uint4 v; } ph, pl;
#pragma unroll
        for (int jj = 0; jj < 8; ++jj) {
          float x = (jj < 4) ? v0[jj] : v1[jj - 4];
          unsigned short h = bf_rne(x);
          ph.s[jj] = h;
          pl.s[jj] = bf_rne(x - bf_to_f(h));
        }
        *(uint4*)&sAh[t * 8] = ph.v;
        *(uint4*)&sAl[t * 8] = pl.v;
      }
      __syncthreads();

      bf16x8 bh[4], bl[4];
#pragma unroll
      for (int ct = 0; ct < 4; ++ct) {
        int off = swz(w * 64 + ct * 16 + l15, q) * 8;
        bh[ct] = *(const bf16x8*)&sBh[off];
        bl[ct] = *(const bf16x8*)&sBl[off];
      }
#pragma unroll
      for (int rt = 0; rt < 4; ++rt) {
        int off = swz(rt * 16 + l15, q) * 8;
        bf16x8 ah = *(const bf16x8*)&sAh[off];
        bf16x8 al = *(const bf16x8*)&sAl[off];
#pragma unroll
        for (int ct = 0; ct < 4; ++ct) {
          acc[rt][ct] = __builtin_amdgcn_mfma_f32_16x16x32_bf16(ah, bh[ct], acc[rt][ct], 0, 0, 0);
          acc[rt][ct] = __builtin_amdgcn_mfma_f32_16x16x32_bf16(ah, bl[ct], acc[rt][ct], 0, 0, 0);
          acc[rt][ct] = __builtin_amdgcn_mfma_f32_16x16x32_bf16(al, bh[ct], acc[rt][ct], 0, 0, 0);
        }
      }
      __syncthreads();
    }

    // epilogue: x1 + b1 -> silu -> *w2 -> reduce wave's 64 cols -> atomic x2
    // (unchanged tree: 8 contributors/token = 4 col-waves x 2 n-chunks)
    float b1v[4], w2v[4];
#pragma unroll
    for (int ct = 0; ct < 4; ++ct) {
      int cidx = nBase + w * 64 + ct * 16 + l15;
      b1v[ct] = b1[cidx];
      w2v[ct] = w2[cidx];
    }
#pragma unroll
    for (int rt = 0; rt < 4; ++rt) {
#pragma unroll
      for (int i = 0; i < 4; ++i) {
        float s = 0.f;
#pragma unroll
        for (int ct = 0; ct < 4; ++ct) {
          float x1 = acc[rt][ct][i] + b1v[ct];
          float h1 = x1 / (1.f + expf(-x1));   // silu
          s += h1 * w2v[ct];
        }
        s += __shfl_xor(s, 1, 64);
        s += __shfl_xor(s, 2, 64);
        s += __shfl_xor(s, 4, 64);
        s += __shfl_xor(s, 8, 64);
        if (l15 == 0)
          unsafeAtomicAdd(&x2[tokBase + rt * 16 + q * 4 + i], s);
      }
    }
  }
}

// ---------- K3: routing + fused aux (last-block pattern) ------------------
// One token per wave (R5-proven). Rank loop now uses shfl_xor: the comparison
// SET is identical (j = e^m visits all 63 others) -> the integer rank r is
// bit-identical; xor addressing is cheaper than bpermute's add/and/lshl.
// The last block to finish performs the aux reduction (saves one launch).
__global__ __launch_bounds__(1024)
void k_route(const float* __restrict__ lg, const float* __restrict__ x2,
             const float* __restrict__ b2, float* __restrict__ out,
             double* __restrict__ tpe_part, double* __restrict__ ks_part,
             int* __restrict__ done) {
  __shared__ double sdt[16 * 64];          // reused as sred in aux phase
  __shared__ double skv[16], sev[16];      // reused as sk/se2 in aux phase
  __shared__ int lastFlag;
  const int t = threadIdx.x, wv = t >> 6, e = t & 63;
  const int tok = blockIdx.x * 16 + wv;
  const float b2v = b2[0];

  const size_t idx = (size_t)tok * NE + e;
  float my = lg[idx];
  float xv = x2[tok] + b2v;
  float d = 1.f / (1.f + expf(-xv));
  float kf = 4.f + 8.f * d;
  int ki = (int)rintf(kf);             // round-half-even, matches jnp.round
  ki = min(max(ki, 4), 12);

  int r = 0;  // stable descending rank (same comparison set as the e+s walk)
#pragma unroll
  for (int m = 1; m < 64; ++m) {
    float o = __shfl_xor(my, m, 64);
    int j = e ^ m;
    r += (o > my || (o == my && j < e)) ? 1 : 0;
  }
  float mx = my;
#pragma unroll
  for (int off = 1; off < 64; off <<= 1) mx = fmaxf(mx, __shfl_xor(mx, off, 64));
  float ex = (r < ki) ? expf(my - mx) : 0.f;
  float sm = ex;
#pragma unroll
  for (int off = 1; off < 64; off <<= 1) sm += __shfl_xor(sm, off, 64);
  float wgt = ex / sm;
  out[idx] = wgt;

  sdt[wv * 64 + e] = (double)wgt;
  if (e == 0) {
    skv[wv] = (double)kf;
    sev[wv] = (double)(d * logf(d + 1e-8f) + (1.f - d) * logf(1.f - d + 1e-8f));
  }
  __syncthreads();
  if (t < 64) {
    double s = 0.0;
#pragma unroll
    for (int wq = 0; wq < 16; ++wq) s += sdt[wq * 64 + t];
    tpe_part[(size_t)blockIdx.x * 64 + t] = s;
  } else if (t == 64) {
    double ks = 0.0, es = 0.0;
#pragma unroll
    for (int wq = 0; wq < 16; ++wq) { ks += skv[wq]; es += sev[wq]; }
    ks_part[blockIdx.x * 2 + 0] = ks;
    ks_part[blockIdx.x * 2 + 1] = es;
  }
  __syncthreads();   // all block stores drained (barrier implies vmcnt(0))
  if (t == 0) {
    __threadfence();
    lastFlag = (atomicAdd(done, 1) == (int)gridDim.x - 1) ? 1 : 0;
  }
  __syncthreads();
  if (!lastFlag) return;

  // ---------- aux phase (last block only; f64 trees unchanged) ----------
  __threadfence();  // acquire all blocks' partials
  const int chunk = t >> 6;  // 16 chunks
  {
    double s = 0.0;
    for (int b = 0; b < 64; ++b)
      s += tpe_part[(size_t)(chunk * 64 + b) * 64 + e];
    sdt[chunk * 64 + e] = s;

    double k0 = ks_part[t * 2 + 0];
    double e0 = ks_part[t * 2 + 1];
#pragma unroll
    for (int off = 1; off < 64; off <<= 1) {
      k0 += __shfl_xor(k0, off, 64);
      e0 += __shfl_xor(e0, off, 64);
    }
    if (e == 0) { skv[chunk] = k0; sev[chunk] = e0; }
  }
  __syncthreads();

  if (t < 64) {
    double x = 0.0;
#pragma unroll
    for (int c = 0; c < 16; ++c) x += sdt[c * 64 + t];
    // x = tokens_per_expert[t]
    double ssum = x;
#pragma unroll
    for (int off = 1; off < 64; off <<= 1) ssum += __shfl_xor(ssum, off, 64);
    double mean = ssum / 64.0;
    double dv = x - mean, v = dv * dv;
#pragma unroll
    for (int off = 1; off < 64; off <<= 1) v += __shfl_xor(v, off, 64);
    double var = v / 63.0;                       // ddof=1
    if (t == 0) {
      double ksum = 0.0, esum = 0.0;
#pragma unroll
      for (int c = 0; c < 16; ++c) { ksum += skv[c]; esum += sev[c]; }
      double avgk = ksum / (double)NTOK;
      double kp = 8.0 - avgk;
      kp = kp > 0.0 ? kp * kp : 0.0;             // relu(BASE_K-avg_k)^2
      double bal = var / (mean + 1e-8);
      double aux = 0.01 * (kp + bal) + 0.001 * (esum / (double)NTOK);
      out[(size_t)NTOK * NE] = (float)aux;
    }
  }
}

// ---------- launch ----------
extern "C" void kernel_launch(void* const* d_in, const int* in_sizes, int n_in,
                              void* d_out, int out_size, void* d_ws, size_t ws_size,
                              hipStream_t stream) {
  const float* hs = (const float*)d_in[0];
  const float* gw = (const float*)d_in[1];
  const float* w1 = (const float*)d_in[2];
  const float* b1 = (const float*)d_in[3];
  const float* w2 = (const float*)d_in[4];
  const float* b2 = (const float*)d_in[5];
  float* out = (float*)d_out;
  char* ws = (char*)d_ws;

  // ws layout (within the 8,454,672 B budget):
  //   [0,       4194304)  gate logits lg (fp32, PLAIN stores now — no zeroing)
  //   [4194304, 4259840)  x2 (zeroed by k_pre)
  //   [4259840, 4259856)  done-counter (zeroed with x2)
  //   [4260368, 6357520)  w1 hi plane (bf16) -- dead after k_main; overlaid
  //                       by k_route partials: tpe_part 524,288 B at
  //                       4260368, ks_part 16,384 B at 4784656
  //   [6357520, 8454672)  w1 lo plane (bf16)
  // gw h/m/l planes (786,432 B) staged in d_out; k_route overwrites d_out
  // afterwards (stream-ordered, every element rewritten).
  float* lg = (float*)ws;
  float* x2 = (float*)(ws + 4194304);
  int*   done = (int*)(ws + 4259840);
  unsigned short* w1h = (unsigned short*)(ws + 4260368);
  unsigned short* w1l = (unsigned short*)(ws + 6357520);
  double* tpe_part = (double*)(ws + 4260368);   // overlays dead w1h
  double* ks_part  = (double*)(ws + 4784656);
  unsigned short* gwh = (unsigned short*)d_out;
  unsigned short* gwm = gwh + NE * HD;
  unsigned short* gwl = gwm + NE * HD;

  // 512 w1-split + 64 gw-split + 1 zero block (x2 + counter)
  k_pre<<<577, 256, 0, stream>>>(w1, w1h, w1l, gw, gwh, gwm, gwl,
                                 (uint4*)(ws + 4194304));
  // 256 gate (bid%3==0) + 512 diff blocks, interleaved -> 3 blocks/CU
  k_main<<<768, 256, 0, stream>>>(hs, gwh, gwm, gwl, lg, w1h, w1l, b1, w2, x2);
  // routing + fused aux (last-block reduction)
  k_route<<<NTOK / 16, 1024, 0, stream>>>(lg, x2, b2, out, tpe_part, ks_part,
                                          done);
}